// Round 1
// baseline (269.305 us; speedup 1.0000x reference)
//
#include <hip/hip_runtime.h>
#include <hip/hip_bf16.h>

#define N_SRCN 200000
#define N_DSTN 50000
#define NEDGE 800000
#define KIN 256
#define NF 192        // H*OUT = 3*64
#define SLOPE 0.2f

typedef __attribute__((ext_vector_type(8))) short bf16x8;
typedef __attribute__((ext_vector_type(4))) float f32x4;

__device__ __forceinline__ unsigned short f2bf(float f) {
    union { float f; unsigned int u; } v; v.f = f;
    unsigned int u = v.u;
    return (unsigned short)((u + 0x7FFFu + ((u >> 16) & 1u)) >> 16);  // RNE
}
__device__ __forceinline__ float bf2f(unsigned short h) {
    union { unsigned int u; float f; } v; v.u = ((unsigned int)h) << 16;
    return v.f;
}

// ---------------- row_ptr: lower_bound of each d in sorted dst ----------------
__global__ void rowptr_kernel(const int* __restrict__ dst, int* __restrict__ rp) {
    int d = blockIdx.x * blockDim.x + threadIdx.x;
    if (d > N_DSTN) return;
    int lo = 0, hi = NEDGE;
    while (lo < hi) {
        int mid = (lo + hi) >> 1;
        if (dst[mid] < d) lo = mid + 1; else hi = mid;
    }
    rp[d] = lo;
}

// ---------------- GEMM: feat = x @ W^T  (bf16 MFMA), feat stored bf16 --------
// grid (3125, 2); block 256 = 4 waves; tile BM=64 x BN=96, full K=256 in LDS.
__launch_bounds__(256, 2)
__global__ void gemm_feat(const float* __restrict__ x, const float* __restrict__ W,
                          unsigned short* __restrict__ feat) {
    __shared__ unsigned short Ab[64 * 256];   // 32 KB, XOR-swizzled
    __shared__ unsigned short Wb[96 * 256];   // 48 KB, XOR-swizzled
    const int rb = blockIdx.x * 64;
    const int cb = blockIdx.y * 96;
    const int t = threadIdx.x;

    // stage A: 64x256 f32 -> bf16 (4096 float4, 16 per thread)
    #pragma unroll
    for (int i = 0; i < 16; ++i) {
        int fi = t + i * 256;
        int r = fi >> 6;
        int k = (fi & 63) << 2;
        const float4 v = *(const float4*)&x[(rb + r) * KIN + k];
        ushort4 s4 = { f2bf(v.x), f2bf(v.y), f2bf(v.z), f2bf(v.w) };
        *(ushort4*)&Ab[r * 256 + (k ^ ((r & 7) << 3))] = s4;
    }
    // stage W half: 96x256 f32 -> bf16 (6144 float4, 24 per thread)
    #pragma unroll
    for (int i = 0; i < 24; ++i) {
        int fi = t + i * 256;
        int r = fi >> 6;
        int k = (fi & 63) << 2;
        const float4 v = *(const float4*)&W[(cb + r) * KIN + k];
        ushort4 s4 = { f2bf(v.x), f2bf(v.y), f2bf(v.z), f2bf(v.w) };
        *(ushort4*)&Wb[r * 256 + (k ^ ((r & 7) << 3))] = s4;
    }
    __syncthreads();

    const int wid = t >> 6, lane = t & 63;
    const int wm = wid >> 1, wn = wid & 1;
    const int al = lane & 15, ah = lane >> 4;
    const int r0 = wm * 32, c0 = wn * 48;

    f32x4 acc[2][3] = {};
    #pragma unroll
    for (int ks = 0; ks < 8; ++ks) {
        const int k0 = ks * 32 + ah * 8;
        bf16x8 av[2], bv[3];
        #pragma unroll
        for (int a = 0; a < 2; ++a) {
            int row = r0 + a * 16 + al;
            av[a] = *(const bf16x8*)&Ab[row * 256 + (k0 ^ ((row & 7) << 3))];
        }
        #pragma unroll
        for (int nt = 0; nt < 3; ++nt) {
            int col = c0 + nt * 16 + al;
            bv[nt] = *(const bf16x8*)&Wb[col * 256 + (k0 ^ ((col & 7) << 3))];
        }
        #pragma unroll
        for (int a = 0; a < 2; ++a)
            #pragma unroll
            for (int nt = 0; nt < 3; ++nt)
                acc[a][nt] = __builtin_amdgcn_mfma_f32_16x16x32_bf16(av[a], bv[nt], acc[a][nt], 0, 0, 0);
    }

    // epilogue: C/D layout col=lane&15, row=(lane>>4)*4+e  [m89-verified]
    #pragma unroll
    for (int a = 0; a < 2; ++a)
        #pragma unroll
        for (int nt = 0; nt < 3; ++nt)
            #pragma unroll
            for (int e = 0; e < 4; ++e) {
                int row = rb + r0 + a * 16 + ah * 4 + e;
                int col = cb + c0 + nt * 16 + al;
                feat[row * NF + col] = f2bf(acc[a][nt][e]);
            }
}

// ---------------- el/er: per-node attention logits ---------------------------
__global__ void elr_kernel(const unsigned short* __restrict__ feat,
                           const float* __restrict__ attn_l, const float* __restrict__ attn_r,
                           float* __restrict__ el, float* __restrict__ er) {
    const int lane = threadIdx.x & 63;
    const int wid = (blockIdx.x * blockDim.x + threadIdx.x) >> 6;
    const int nw = (gridDim.x * blockDim.x) >> 6;
    float alv[3], arv[3];
    #pragma unroll
    for (int k = 0; k < 3; ++k) { alv[k] = attn_l[k * 64 + lane]; arv[k] = attn_r[k * 64 + lane]; }
    for (int n = wid; n < N_SRCN; n += nw) {
        const bool isdst = n < N_DSTN;
        float sl[3], sr[3];
        #pragma unroll
        for (int k = 0; k < 3; ++k) {
            float f = bf2f(feat[n * NF + k * 64 + lane]);
            sl[k] = f * alv[k];
            sr[k] = f * arv[k];
        }
        #pragma unroll
        for (int off = 32; off; off >>= 1) {
            #pragma unroll
            for (int k = 0; k < 3; ++k) {
                sl[k] += __shfl_xor(sl[k], off);
                sr[k] += __shfl_xor(sr[k], off);
            }
        }
        if (lane == 0) {
            #pragma unroll
            for (int k = 0; k < 3; ++k) {
                el[n * 3 + k] = sl[k];
                if (isdst) er[n * 3 + k] = sr[k];
            }
        }
    }
}

// ---------------- gather: edge softmax + weighted feat accumulate ------------
// one wave per dst node
__launch_bounds__(256)
__global__ void gather_kernel(const unsigned short* __restrict__ feat,
                              const float* __restrict__ el, const float* __restrict__ er,
                              const int* __restrict__ src, const int* __restrict__ rp,
                              float* __restrict__ out) {
    const int lane = threadIdx.x & 63;
    const int d = (blockIdx.x * blockDim.x + threadIdx.x) >> 6;
    if (d >= N_DSTN) return;
    const int lo = rp[d], hi = rp[d + 1];
    const float er0 = er[d * 3 + 0], er1 = er[d * 3 + 1], er2 = er[d * 3 + 2];

    // pass A: per-head max over incoming edges (lane-parallel)
    float m0 = -1e30f, m1 = -1e30f, m2 = -1e30f;
    for (int i = lo + lane; i < hi; i += 64) {
        int s = src[i];
        float e0 = el[s * 3 + 0] + er0; e0 = e0 >= 0.f ? e0 : SLOPE * e0;
        float e1 = el[s * 3 + 1] + er1; e1 = e1 >= 0.f ? e1 : SLOPE * e1;
        float e2 = el[s * 3 + 2] + er2; e2 = e2 >= 0.f ? e2 : SLOPE * e2;
        m0 = fmaxf(m0, e0); m1 = fmaxf(m1, e1); m2 = fmaxf(m2, e2);
    }
    #pragma unroll
    for (int off = 32; off; off >>= 1) {
        m0 = fmaxf(m0, __shfl_xor(m0, off));
        m1 = fmaxf(m1, __shfl_xor(m1, off));
        m2 = fmaxf(m2, __shfl_xor(m2, off));
    }

    // pass B: exp-sum + weighted accumulate (lane owns feature `lane` of each head)
    float a0 = 0.f, a1 = 0.f, a2 = 0.f, s0 = 0.f, s1 = 0.f, s2 = 0.f;
    for (int base = lo; base < hi; base += 64) {
        int cnt = min(64, hi - base);
        int sv = 0; float e0 = 0.f, e1 = 0.f, e2 = 0.f;
        if (lane < cnt) {
            sv = src[base + lane];
            e0 = el[sv * 3 + 0] + er0; e0 = (e0 >= 0.f ? e0 : SLOPE * e0) - m0;
            e1 = el[sv * 3 + 1] + er1; e1 = (e1 >= 0.f ? e1 : SLOPE * e1) - m1;
            e2 = el[sv * 3 + 2] + er2; e2 = (e2 >= 0.f ? e2 : SLOPE * e2) - m2;
        }
        for (int j = 0; j < cnt; ++j) {
            int sj = __shfl(sv, j);
            float w0 = __expf(__shfl(e0, j));
            float w1 = __expf(__shfl(e1, j));
            float w2 = __expf(__shfl(e2, j));
            s0 += w0; s1 += w1; s2 += w2;
            const unsigned short* fp = &feat[sj * NF];
            a0 += w0 * bf2f(fp[lane]);
            a1 += w1 * bf2f(fp[64 + lane]);
            a2 += w2 * bf2f(fp[128 + lane]);
        }
    }
    if (hi == lo) { s0 = 1.f; s1 = 1.f; s2 = 1.f; }
    float* op = &out[d * NF];
    op[lane]       = a0 / s0;
    op[64 + lane]  = a1 / s1;
    op[128 + lane] = a2 / s2;
}

extern "C" void kernel_launch(void* const* d_in, const int* in_sizes, int n_in,
                              void* d_out, int out_size, void* d_ws, size_t ws_size,
                              hipStream_t stream) {
    const float* x      = (const float*)d_in[0];
    const float* W      = (const float*)d_in[1];
    const float* attn_l = (const float*)d_in[2];
    const float* attn_r = (const float*)d_in[3];
    const int*   src    = (const int*)d_in[4];
    const int*   dst    = (const int*)d_in[5];
    float* out = (float*)d_out;

    char* ws = (char*)d_ws;
    unsigned short* feat = (unsigned short*)ws;            // 200000*192*2 = 76,800,000 B
    float* el = (float*)(ws + 76800000);                   // 200000*3*4   =  2,400,000 B
    float* er = (float*)(ws + 79200000);                   // 50000*3*4    =    600,000 B
    int*   rp = (int*)(ws + 79800000);                     // 50001*4      =    200,004 B

    rowptr_kernel<<<(N_DSTN + 1 + 255) / 256, 256, 0, stream>>>(dst, rp);
    gemm_feat<<<dim3(3125, 2), 256, 0, stream>>>(x, W, feat);
    elr_kernel<<<1024, 256, 0, stream>>>(feat, attn_l, attn_r, el, er);
    gather_kernel<<<12500, 256, 0, stream>>>(feat, el, er, src, rp, out);
}

// Round 2
// 185.880 us; speedup vs baseline: 1.4488x; 1.4488x over previous
//
#include <hip/hip_runtime.h>
#include <hip/hip_bf16.h>

#define N_SRCN 200000
#define N_DSTN 50000
#define NEDGE 800000
#define KIN 256
#define NF 192        // H*OUT = 3*64
#define SLOPE 0.2f

typedef __attribute__((ext_vector_type(8))) short bf16x8;
typedef __attribute__((ext_vector_type(4))) float f32x4;

__device__ __forceinline__ unsigned short f2bf(float f) {
    union { float f; unsigned int u; } v; v.f = f;
    unsigned int u = v.u;
    return (unsigned short)((u + 0x7FFFu + ((u >> 16) & 1u)) >> 16);  // RNE
}
__device__ __forceinline__ float bf2f(unsigned short h) {
    union { unsigned int u; float f; } v; v.u = ((unsigned int)h) << 16;
    return v.f;
}
__device__ __forceinline__ unsigned int cvt2(float lo, float hi) {
    __hip_bfloat162 h = __float22bfloat162_rn(float2{lo, hi});
    union { __hip_bfloat162 h; unsigned int u; } c; c.h = h;
    return c.u;
}

// ---------------- prep: pack W (f32 [192][256]) into bf16 fragment-major -----
// Wp[((ks*12 + nt)*64 + lane)*8 + j] = bf16(W[nt*16 + (lane&15)][ks*32 + (lane>>4)*8 + j])
__global__ void prep_w(const float* __restrict__ W, unsigned short* __restrict__ Wp) {
    int tid = blockIdx.x * blockDim.x + threadIdx.x;
    if (tid >= 12 * 8 * 64) return;
    int lane = tid & 63;
    int g = tid >> 6;
    int nt = g % 12, ks = g / 12;
    int col = nt * 16 + (lane & 15);
    int k = ks * 32 + (lane >> 4) * 8;
    const float* wsrc = &W[col * KIN + k];
    unsigned short* o = &Wp[tid * 8];
    #pragma unroll
    for (int j = 0; j < 8; ++j) o[j] = f2bf(wsrc[j]);
}

// ---------------- row_ptr: lower_bound of each d in sorted dst ----------------
__global__ void rowptr_kernel(const int* __restrict__ dst, int* __restrict__ rp) {
    int d = blockIdx.x * blockDim.x + threadIdx.x;
    if (d > N_DSTN) return;
    int lo = 0, hi = NEDGE;
    while (lo < hi) {
        int mid = (lo + hi) >> 1;
        if (dst[mid] < d) lo = mid + 1; else hi = mid;
    }
    rp[d] = lo;
}

// ---------------- GEMM: feat = x @ W^T (bf16 MFMA) + fused el/er -------------
// grid 3125 blocks x 256 thr. Wave w owns rows [blk*64 + w*16, +16), ALL 192 cols.
// No LDS, no barrier: A-frags straight from global f32 (read-once), B-frags from
// packed bf16 W (L1/L2-resident, coalesced 1KB per frag).
__launch_bounds__(256)
__global__ void gemm_feat(const float* __restrict__ x, const unsigned short* __restrict__ Wp,
                          const float* __restrict__ attn_l, const float* __restrict__ attn_r,
                          unsigned short* __restrict__ feat,
                          float* __restrict__ el, float* __restrict__ er) {
    const int t = threadIdx.x;
    const int wid = t >> 6, lane = t & 63;
    const int al = lane & 15, ah = lane >> 4;
    const int r0 = blockIdx.x * 64 + wid * 16;

    const float* xrow = &x[(size_t)(r0 + al) * KIN];
    f32x4 acc[12] = {};

    #pragma unroll
    for (int ks = 0; ks < 8; ++ks) {
        const int k0 = ks * 32 + ah * 8;
        const float4 a0 = *(const float4*)&xrow[k0];
        const float4 a1 = *(const float4*)&xrow[k0 + 4];
        union { bf16x8 v; unsigned int u[4]; } av;
        av.u[0] = cvt2(a0.x, a0.y);
        av.u[1] = cvt2(a0.z, a0.w);
        av.u[2] = cvt2(a1.x, a1.y);
        av.u[3] = cvt2(a1.z, a1.w);
        const unsigned short* wbase = &Wp[(size_t)(ks * 12) * 64 * 8 + lane * 8];
        #pragma unroll
        for (int nt = 0; nt < 12; ++nt) {
            bf16x8 bv = *(const bf16x8*)&wbase[nt * 64 * 8];
            acc[nt] = __builtin_amdgcn_mfma_f32_16x16x32_bf16(av.v, bv, acc[nt], 0, 0, 0);
        }
    }

    // epilogue 1: feat store (C/D layout: col=al+nt*16, row=ah*4+e  [m89])
    #pragma unroll
    for (int nt = 0; nt < 12; ++nt) {
        const int col = nt * 16 + al;
        #pragma unroll
        for (int e = 0; e < 4; ++e) {
            const int row = r0 + ah * 4 + e;
            feat[(size_t)row * NF + col] = f2bf(acc[nt][e]);
        }
    }

    // epilogue 2: fused el/er (wave holds full rows). head h = cols [h*64, h*64+64)
    float Al[12], Ar[12];
    #pragma unroll
    for (int nt = 0; nt < 12; ++nt) {
        Al[nt] = attn_l[nt * 16 + al];
        Ar[nt] = attn_r[nt * 16 + al];
    }
    #pragma unroll
    for (int h = 0; h < 3; ++h) {
        #pragma unroll
        for (int e = 0; e < 4; ++e) {
            float sl = 0.f, sr = 0.f;
            #pragma unroll
            for (int q = 0; q < 4; ++q) {
                const int nt = h * 4 + q;
                sl += acc[nt][e] * Al[nt];
                sr += acc[nt][e] * Ar[nt];
            }
            #pragma unroll
            for (int m = 1; m <= 8; m <<= 1) {
                sl += __shfl_xor(sl, m);
                sr += __shfl_xor(sr, m);
            }
            if (al == 0) {
                const int row = r0 + ah * 4 + e;
                el[row * 3 + h] = sl;
                if (row < N_DSTN) er[row * 3 + h] = sr;
            }
        }
    }
}

// ---------------- gather: edge softmax (no max shift) + weighted accumulate --
// one wave per dst node; lane owns feature `lane` of each head
__launch_bounds__(256)
__global__ void gather_kernel(const unsigned short* __restrict__ feat,
                              const float* __restrict__ el, const float* __restrict__ er,
                              const int* __restrict__ src, const int* __restrict__ rp,
                              float* __restrict__ out) {
    const int lane = threadIdx.x & 63;
    const int d = (blockIdx.x * blockDim.x + threadIdx.x) >> 6;
    if (d >= N_DSTN) return;
    const int lo = rp[d], hi = rp[d + 1];
    const float er0 = er[d * 3 + 0], er1 = er[d * 3 + 1], er2 = er[d * 3 + 2];

    float a0 = 0.f, a1 = 0.f, a2 = 0.f, s0 = 0.f, s1 = 0.f, s2 = 0.f;
    for (int base = lo; base < hi; base += 64) {
        const int cnt = min(64, hi - base);
        int sv = 0; float w0 = 0.f, w1 = 0.f, w2 = 0.f;
        if (lane < cnt) {
            sv = src[base + lane];
            float e0 = el[sv * 3 + 0] + er0; e0 = e0 >= 0.f ? e0 : SLOPE * e0; w0 = __expf(e0);
            float e1 = el[sv * 3 + 1] + er1; e1 = e1 >= 0.f ? e1 : SLOPE * e1; w1 = __expf(e1);
            float e2 = el[sv * 3 + 2] + er2; e2 = e2 >= 0.f ? e2 : SLOPE * e2; w2 = __expf(e2);
        }
        for (int j = 0; j < cnt; ++j) {
            const int sj = __shfl(sv, j);
            const float u0 = __shfl(w0, j);
            const float u1 = __shfl(w1, j);
            const float u2 = __shfl(w2, j);
            s0 += u0; s1 += u1; s2 += u2;
            const unsigned short* fp = &feat[(size_t)sj * NF];
            a0 += u0 * bf2f(fp[lane]);
            a1 += u1 * bf2f(fp[64 + lane]);
            a2 += u2 * bf2f(fp[128 + lane]);
        }
    }
    if (hi == lo) { s0 = 1.f; s1 = 1.f; s2 = 1.f; }
    float* op = &out[(size_t)d * NF];
    op[lane]       = a0 / s0;
    op[64 + lane]  = a1 / s1;
    op[128 + lane] = a2 / s2;
}

extern "C" void kernel_launch(void* const* d_in, const int* in_sizes, int n_in,
                              void* d_out, int out_size, void* d_ws, size_t ws_size,
                              hipStream_t stream) {
    const float* x      = (const float*)d_in[0];
    const float* W      = (const float*)d_in[1];
    const float* attn_l = (const float*)d_in[2];
    const float* attn_r = (const float*)d_in[3];
    const int*   src    = (const int*)d_in[4];
    const int*   dst    = (const int*)d_in[5];
    float* out = (float*)d_out;

    char* ws = (char*)d_ws;
    unsigned short* feat = (unsigned short*)ws;             // 76,800,000 B
    float* el = (float*)(ws + 76800000);                    //  2,400,000 B
    float* er = (float*)(ws + 79200000);                    //    600,000 B
    unsigned short* Wp = (unsigned short*)(ws + 79800000);  //     98,304 B
    int*   rp = (int*)(ws + 79898304);                      //    200,004 B

    prep_w<<<24, 256, 0, stream>>>(W, Wp);
    rowptr_kernel<<<(N_DSTN + 1 + 255) / 256, 256, 0, stream>>>(dst, rp);
    gemm_feat<<<3125, 256, 0, stream>>>(x, Wp, attn_l, attn_r, feat, el, er);
    gather_kernel<<<12500, 256, 0, stream>>>(feat, el, er, src, rp, out);
}